// Round 8
// baseline (974.360 us; speedup 1.0000x reference)
//
#include <hip/hip_runtime.h>
#include <hip/hip_bf16.h>

#define N_NODES 100000
#define N_EDGES 1600000

static __device__ __forceinline__ float us2f(unsigned short u) {
    union { unsigned int i; float f; } cv; cv.i = ((unsigned int)u) << 16; return cv.f;
}
static __device__ __forceinline__ unsigned short f2us(float f) {
    __hip_bfloat16 b = __float2bfloat16(f);
    union { __hip_bfloat16 b; unsigned short u; } cv; cv.b = b; return cv.u;
}
static __device__ __forceinline__ float elu_fast(float v) {
    return v > 0.f ? v : (__expf(v) - 1.0f);
}

// ---------------- inv: single-wave Gauss-Jordan; outputs MmT[j*32+c] = (A^T (I-A^T)^{-1})[c][j]
__global__ __launch_bounds__(64) void k_inv(const float* __restrict__ A,
                                            float* __restrict__ MmT) {
    __shared__ float Af[1024];
    __shared__ float aug[32 * 65];   // 64 active cols: 0..31 = I-A^T, 32..63 = I
    __shared__ float fac[32];
    __shared__ float pv_s;
    int t = threadIdx.x;
    for (int i = t; i < 1024; i += 64) Af[i] = A[i];
    __syncthreads();
    for (int i = t; i < 2048; i += 64) {
        int r = i >> 6, c = i & 63;
        float v;
        if (c < 32) v = (r == c ? 1.0f : 0.0f) - Af[c * 32 + r];
        else        v = ((c - 32) == r ? 1.0f : 0.0f);
        aug[r * 65 + c] = v;
    }
    __syncthreads();
    for (int k = 0; k < 32; ++k) {
        if (t == 0) pv_s = 1.0f / aug[k * 65 + k];
        __syncthreads();
        aug[k * 65 + t] *= pv_s;
        __syncthreads();
        if (t < 32) fac[t] = aug[t * 65 + k];
        __syncthreads();
        #pragma unroll 4
        for (int i = t; i < 2048; i += 64) {
            int r = i >> 6, c = i & 63;
            if (r != k) aug[r * 65 + c] -= fac[r] * aug[k * 65 + c];
        }
        __syncthreads();
    }
    // MmT[j*32+c] = sum_k A^T[c][k] * Cm[k][j] = sum_k Af[k*32+c] * aug[k*65+32+j]
    for (int i = t; i < 1024; i += 64) {
        int j = i >> 5, c = i & 31;
        float s = 0.f;
        #pragma unroll
        for (int k = 0; k < 32; ++k) s += Af[k * 32 + c] * aug[k * 65 + 32 + j];
        MmT[i] = s;
    }
}

// ---------------- fold: Wcomb[h][c*4+d] = sum_j Mm[c][j]*Wm[h*128+j*4+d]  (16 blocks) --------
__global__ __launch_bounds__(256) void k_fold(const float* __restrict__ MmT,
                                              const float* __restrict__ Wm,
                                              float* __restrict__ Wcomb) {
    __shared__ float MmTs[1024];
    int tid = threadIdx.x;
    for (int i = tid; i < 1024; i += 256) MmTs[i] = MmT[i];
    __syncthreads();
    int o = blockIdx.x * 256 + tid;       // o = h*32 + c
    int h = o >> 5, c = o & 31;
    float4 s = {0.f, 0.f, 0.f, 0.f};
    #pragma unroll
    for (int j = 0; j < 32; ++j) {
        float m = MmTs[j * 32 + c];       // lanes consecutive in c: conflict-free
        float4 w = ((const float4*)Wm)[h * 32 + j];
        s.x += m * w.x; s.y += m * w.y; s.z += m * w.z; s.w += m * w.w;
    }
    ((float4*)Wcomb)[o] = s;
}

// ---------------- CSR build: histogram -> multi-block scan -> scatter ------------------------
__global__ __launch_bounds__(256) void k_hist(const int* __restrict__ edst,
                                              unsigned int* __restrict__ deg) {
    int e = blockIdx.x * 256 + threadIdx.x;
    atomicAdd(&deg[edst[e]], 1u);
}

__global__ __launch_bounds__(256) void k_scanA(const unsigned int* __restrict__ deg,
                                               unsigned int* __restrict__ row_start,
                                               unsigned int* __restrict__ blk_sums) {
    __shared__ unsigned int sums[256];
    int tid = threadIdx.x;
    int gid = blockIdx.x * 256 + tid;
    uint4 d = ((const uint4*)deg)[gid];
    unsigned int p1 = d.x, p2 = d.x + d.y, p3 = p2 + d.z;
    unsigned int tsum = p3 + d.w;
    sums[tid] = tsum;
    __syncthreads();
    for (int off = 1; off < 256; off <<= 1) {
        unsigned int v = (tid >= off) ? sums[tid - off] : 0u;
        __syncthreads();
        sums[tid] += v;
        __syncthreads();
    }
    unsigned int excl = sums[tid] - tsum;
    int eb = gid * 4;
    if (eb + 0 < N_NODES) row_start[eb + 0] = excl;
    if (eb + 1 < N_NODES) row_start[eb + 1] = excl + p1;
    if (eb + 2 < N_NODES) row_start[eb + 2] = excl + p2;
    if (eb + 3 < N_NODES) row_start[eb + 3] = excl + p3;
    if (tid == 255) blk_sums[blockIdx.x] = sums[255];
}

__global__ __launch_bounds__(128) void k_scanB(unsigned int* __restrict__ blk_sums) {
    __shared__ unsigned int s[128];
    int tid = threadIdx.x;
    unsigned int v = (tid < 98) ? blk_sums[tid] : 0u;
    s[tid] = v;
    __syncthreads();
    for (int off = 1; off < 128; off <<= 1) {
        unsigned int x = (tid >= off) ? s[tid - off] : 0u;
        __syncthreads();
        s[tid] += x;
        __syncthreads();
    }
    if (tid < 98) blk_sums[tid] = s[tid] - v;
}

__global__ __launch_bounds__(256) void k_scanC(unsigned int* __restrict__ row_start,
                                               unsigned int* __restrict__ cursor,
                                               const unsigned int* __restrict__ blk_sums) {
    int tid = threadIdx.x;
    unsigned int off = blk_sums[blockIdx.x];
    int eb = (blockIdx.x * 256 + tid) * 4;
    #pragma unroll
    for (int k = 0; k < 4; ++k) {
        int idx = eb + k;
        if (idx < N_NODES) {
            unsigned int u = row_start[idx] + off;
            row_start[idx] = u;
            cursor[idx] = u;
        }
    }
    if (blockIdx.x == 0 && tid == 0) row_start[N_NODES] = N_EDGES;
}

__global__ __launch_bounds__(256) void k_scatter(const int* __restrict__ esrc,
                                                 const int* __restrict__ edst,
                                                 const float* __restrict__ evalv,
                                                 unsigned int* __restrict__ cursor,
                                                 uint2* __restrict__ edge_sorted) {
    int e = blockIdx.x * 256 + threadIdx.x;
    unsigned int p = atomicAdd(&cursor[edst[e]], 1u);
    uint2 ev;
    ev.x = (unsigned int)esrc[e];
    ev.y = __float_as_uint(evalv[e]);
    edge_sorted[p] = ev;
}

// ---------------- gather1: S1[n][c] = sum_e val*X[src][c]  (no LDS, unroll x4) ---------------
__global__ __launch_bounds__(256) void k_gather1(const unsigned int* __restrict__ row_start,
                                                 const uint2* __restrict__ edge_sorted,
                                                 const float* __restrict__ X,
                                                 float* __restrict__ S1) {
    int lane = threadIdx.x & 31;
    int n = blockIdx.x * 8 + (threadIdx.x >> 5);
    unsigned int i = row_start[n], e = row_start[n + 1];
    float a0 = 0.f, a1 = 0.f, a2 = 0.f, a3 = 0.f;
    for (; i + 4 <= e; i += 4) {
        uint2 ea = edge_sorted[i + 0], eb = edge_sorted[i + 1];
        uint2 ec = edge_sorted[i + 2], ed = edge_sorted[i + 3];
        float xa = X[(size_t)ea.x * 32 + lane];
        float xb = X[(size_t)eb.x * 32 + lane];
        float xc = X[(size_t)ec.x * 32 + lane];
        float xd = X[(size_t)ed.x * 32 + lane];
        a0 += __uint_as_float(ea.y) * xa;
        a1 += __uint_as_float(eb.y) * xb;
        a2 += __uint_as_float(ec.y) * xc;
        a3 += __uint_as_float(ed.y) * xd;
    }
    for (; i < e; ++i) {
        uint2 ea = edge_sorted[i];
        a0 += __uint_as_float(ea.y) * X[(size_t)ea.x * 32 + lane];
    }
    S1[(size_t)n * 32 + lane] = (a0 + a1) + (a2 + a3);
}

// ---------------- gemm1: hidden = bf16(relu(S1 @ W_base)), [32 rows x 128 cols]/block --------
__global__ __launch_bounds__(256) void k_gemm1(const float* __restrict__ S1,
                                               const float* __restrict__ Wb,
                                               unsigned short* __restrict__ hidden) {
    __shared__ float Wb_s[4096];      // [k][j] 32x128 (16 KB)
    __shared__ float S1s[32 * 36];
    int tid = threadIdx.x;
    int n0 = blockIdx.x * 32;
    for (int i = tid; i < 1024; i += 256)
        ((float4*)Wb_s)[i] = ((const float4*)Wb)[i];
    {
        int r = tid >> 3, cq = tid & 7;
        *(float4*)&S1s[r * 36 + cq * 4] = *(const float4*)&S1[(size_t)(n0 + r) * 32 + cq * 4];
    }
    __syncthreads();
    int q = (tid & 31) * 4;
    int r0 = tid >> 5;
    float4 acc[4];
    #pragma unroll
    for (int i = 0; i < 4; ++i) acc[i] = make_float4(0.f, 0.f, 0.f, 0.f);
    for (int k4 = 0; k4 < 32; k4 += 4) {
        float4 s[4];
        #pragma unroll
        for (int i = 0; i < 4; ++i) s[i] = *(const float4*)&S1s[(r0 + i * 8) * 36 + k4];
        #pragma unroll
        for (int kk = 0; kk < 4; ++kk) {
            float4 w = *(const float4*)&Wb_s[(k4 + kk) * 128 + q];
            #pragma unroll
            for (int i = 0; i < 4; ++i) {
                float v = (&s[i].x)[kk];
                acc[i].x += v * w.x; acc[i].y += v * w.y;
                acc[i].z += v * w.z; acc[i].w += v * w.w;
            }
        }
    }
    #pragma unroll
    for (int i = 0; i < 4; ++i) {
        ushort4 o;
        o.x = f2us(fmaxf(acc[i].x, 0.f)); o.y = f2us(fmaxf(acc[i].y, 0.f));
        o.z = f2us(fmaxf(acc[i].z, 0.f)); o.w = f2us(fmaxf(acc[i].w, 0.f));
        *(ushort4*)&hidden[(size_t)(n0 + r0 + i * 8) * 128 + q] = o;
    }
}

// ---------------- gather2: S2[n][0:128] (bf16) = sum_e val*hidden[src]  (no LDS, unroll x4) ---
__global__ __launch_bounds__(256) void k_gather2(const unsigned int* __restrict__ row_start,
                                                 const uint2* __restrict__ edge_sorted,
                                                 const unsigned short* __restrict__ hidden,
                                                 unsigned short* __restrict__ S2) {
    int lane = threadIdx.x & 31;
    int n = blockIdx.x * 8 + (threadIdx.x >> 5);
    unsigned int i = row_start[n], e = row_start[n + 1];
    float4 A0 = {0, 0, 0, 0}, A1 = {0, 0, 0, 0}, A2 = {0, 0, 0, 0}, A3 = {0, 0, 0, 0};
    for (; i + 4 <= e; i += 4) {
        uint2 ea = edge_sorted[i + 0], eb = edge_sorted[i + 1];
        uint2 ec = edge_sorted[i + 2], ed = edge_sorted[i + 3];
        ushort4 ha = *(const ushort4*)&hidden[(size_t)ea.x * 128 + lane * 4];
        ushort4 hb = *(const ushort4*)&hidden[(size_t)eb.x * 128 + lane * 4];
        ushort4 hc = *(const ushort4*)&hidden[(size_t)ec.x * 128 + lane * 4];
        ushort4 hd = *(const ushort4*)&hidden[(size_t)ed.x * 128 + lane * 4];
        float va = __uint_as_float(ea.y), vb = __uint_as_float(eb.y);
        float vc = __uint_as_float(ec.y), vd = __uint_as_float(ed.y);
        A0.x += va * us2f(ha.x); A0.y += va * us2f(ha.y); A0.z += va * us2f(ha.z); A0.w += va * us2f(ha.w);
        A1.x += vb * us2f(hb.x); A1.y += vb * us2f(hb.y); A1.z += vb * us2f(hb.z); A1.w += vb * us2f(hb.w);
        A2.x += vc * us2f(hc.x); A2.y += vc * us2f(hc.y); A2.z += vc * us2f(hc.z); A2.w += vc * us2f(hc.w);
        A3.x += vd * us2f(hd.x); A3.y += vd * us2f(hd.y); A3.z += vd * us2f(hd.z); A3.w += vd * us2f(hd.w);
    }
    for (; i < e; ++i) {
        uint2 ea = edge_sorted[i];
        float v = __uint_as_float(ea.y);
        ushort4 h = *(const ushort4*)&hidden[(size_t)ea.x * 128 + lane * 4];
        A0.x += v * us2f(h.x); A0.y += v * us2f(h.y); A0.z += v * us2f(h.z); A0.w += v * us2f(h.w);
    }
    float4 acc;
    acc.x = (A0.x + A1.x) + (A2.x + A3.x);
    acc.y = (A0.y + A1.y) + (A2.y + A3.y);
    acc.z = (A0.z + A1.z) + (A2.z + A3.z);
    acc.w = (A0.w + A1.w) + (A2.w + A3.w);
    ushort4 o;
    o.x = f2us(acc.x); o.y = f2us(acc.y); o.z = f2us(acc.z); o.w = f2us(acc.w);
    *(ushort4*)&S2[(size_t)n * 128 + lane * 4] = o;
}

// ---------------- gemm2: masked_T = (S2 @ Wcomb)^T, [32 rows x 64 cols]/block ----------------
__global__ __launch_bounds__(256) void k_gemm2(const unsigned short* __restrict__ S2,
                                               const float* __restrict__ Wc,
                                               unsigned short* __restrict__ masked_T) {
    __shared__ float Wc_s[128 * 64];
    __shared__ float S2s[32 * 132];
    __shared__ unsigned short Tt[64 * 40];
    int tid = threadIdx.x;
    int rb = blockIdx.x >> 1;
    int j0 = (blockIdx.x & 1) * 64;
    int n0 = rb * 32;
    for (int idx = tid; idx < 2048; idx += 256) {
        int k = idx >> 4, jq = idx & 15;
        *(float4*)&Wc_s[k * 64 + jq * 4] = *(const float4*)&Wc[k * 128 + j0 + jq * 4];
    }
    for (int idx = tid; idx < 1024; idx += 256) {
        int r = idx >> 5, kq = idx & 31;
        ushort4 h = *(const ushort4*)&S2[(size_t)(n0 + r) * 128 + kq * 4];
        float4 f = {us2f(h.x), us2f(h.y), us2f(h.z), us2f(h.w)};
        *(float4*)&S2s[r * 132 + kq * 4] = f;
    }
    __syncthreads();
    int q = (tid & 15) * 4;
    int r0 = tid >> 4;
    float4 a0 = {0, 0, 0, 0}, a1 = {0, 0, 0, 0};
    for (int k4 = 0; k4 < 128; k4 += 4) {
        float4 s0 = *(const float4*)&S2s[r0 * 132 + k4];
        float4 s1 = *(const float4*)&S2s[(r0 + 16) * 132 + k4];
        #pragma unroll
        for (int kk = 0; kk < 4; ++kk) {
            float v0 = (&s0.x)[kk];
            float v1 = (&s1.x)[kk];
            float4 w = *(const float4*)&Wc_s[(k4 + kk) * 64 + q];
            a0.x += v0 * w.x; a0.y += v0 * w.y; a0.z += v0 * w.z; a0.w += v0 * w.w;
            a1.x += v1 * w.x; a1.y += v1 * w.y; a1.z += v1 * w.z; a1.w += v1 * w.w;
        }
    }
    #pragma unroll
    for (int c = 0; c < 4; ++c) {
        Tt[(q + c) * 40 + r0]      = f2us((&a0.x)[c]);
        Tt[(q + c) * 40 + r0 + 16] = f2us((&a1.x)[c]);
    }
    __syncthreads();
    int j = tid >> 2, seg = tid & 3;
    uint4 pk = *(const uint4*)&Tt[j * 40 + seg * 8];
    *(uint4*)&masked_T[(size_t)(j0 + j) * N_NODES + n0 + seg * 8] = pk;
}

// ---------------- noise head: rec_noise = sqrt(lambda) * (noise @ Wrec) ----------------------
__global__ __launch_bounds__(256) void k_noise(const float* __restrict__ noise,
                                               const float* __restrict__ Wrec,
                                               float* __restrict__ rec_noise) {
    __shared__ float Wr[4096];
    __shared__ float Ns[64 * 132];
    int tid = threadIdx.x;
    int n0 = blockIdx.x * 64;
    for (int i = tid; i < 1024; i += 256)
        ((float4*)Wr)[i] = ((const float4*)Wrec)[i];
    for (int i = tid; i < 2048; i += 256) {
        int row = i >> 5, c4 = i & 31;
        int n = n0 + row;
        float4 v = (n < N_NODES) ? ((const float4*)(noise + (size_t)n * 128))[c4]
                                 : make_float4(0.f, 0.f, 0.f, 0.f);
        *(float4*)&Ns[row * 132 + c4 * 4] = v;
    }
    __syncthreads();
    int r = tid >> 2, q = (tid & 3) * 8;
    float4 acc0 = {0, 0, 0, 0}, acc1 = {0, 0, 0, 0};
    for (int k = 0; k < 128; ++k) {
        float nv = Ns[r * 132 + k];
        float4 w0 = *(const float4*)&Wr[k * 32 + q];
        float4 w1 = *(const float4*)&Wr[k * 32 + q + 4];
        acc0.x += nv * w0.x; acc0.y += nv * w0.y; acc0.z += nv * w0.z; acc0.w += nv * w0.w;
        acc1.x += nv * w1.x; acc1.y += nv * w1.y; acc1.z += nv * w1.z; acc1.w += nv * w1.w;
    }
    const float SQ = 0.03162277660168379f;
    acc0.x *= SQ; acc0.y *= SQ; acc0.z *= SQ; acc0.w *= SQ;
    acc1.x *= SQ; acc1.y *= SQ; acc1.z *= SQ; acc1.w *= SQ;
    int n = n0 + r;
    if (n < N_NODES) {
        ((float4*)(rec_noise + (size_t)n * 32 + q))[0] = acc0;
        ((float4*)(rec_noise + (size_t)n * 32 + q + 4))[0] = acc1;
    }
}

// ---------------- nodez: 2 nodes/lane, b128 LDS weight broadcasts, 64-thread blocks ----------
__global__ __launch_bounds__(64) void k_nodez(const unsigned short* __restrict__ masked_T,
                                              const float* __restrict__ rec_noise,
                                              const float* __restrict__ Wz1,
                                              const float* __restrict__ bz1,
                                              const float* __restrict__ Wz2,
                                              const float* __restrict__ bz2,
                                              const float* __restrict__ Wrec,
                                              const float* __restrict__ brec,
                                              float* __restrict__ out) {
    __shared__ float4 Wz1s[1024];   // [c][d][g/4]: c*32 + d*8 + g4
    __shared__ float4 Wz2s[1024];   // [c][g][d]:   c*32 + g (float4 over d)
    __shared__ float4 Wrecs[1024];  // [h][o/4]:    h*8 + oq
    __shared__ float4 bz1s[256];    // [c][g/4]:    c*8 + g4
    __shared__ float4 bz2s[32];     // [c] over d
    __shared__ float4 brecs[8];
    int tid = threadIdx.x;
    for (int i = tid; i < 1024; i += 64) {
        Wz1s[i] = ((const float4*)Wz1)[i];
        Wz2s[i] = ((const float4*)Wz2)[i];
        Wrecs[i] = ((const float4*)Wrec)[i];
    }
    for (int i = tid; i < 256; i += 64) bz1s[i] = ((const float4*)bz1)[i];
    if (tid < 32) bz2s[tid] = ((const float4*)bz2)[tid];
    if (tid < 8) brecs[tid] = ((const float4*)brec)[tid];
    __syncthreads();

    int nA = blockIdx.x * 128 + tid;
    int nB = nA + 64;
    bool okA = nA < N_NODES, okB = nB < N_NODES;
    int mA = okA ? nA : (N_NODES - 1);
    int mB = okB ? nB : (N_NODES - 1);

    float4 recA[8], recB[8];
    #pragma unroll
    for (int q = 0; q < 8; ++q) {
        float4 rA = ((const float4*)(rec_noise + (size_t)mA * 32))[q];
        float4 rB = ((const float4*)(rec_noise + (size_t)mB * 32))[q];
        float4 b = brecs[q];
        recA[q].x = b.x + rA.x; recA[q].y = b.y + rA.y; recA[q].z = b.z + rA.z; recA[q].w = b.w + rA.w;
        recB[q].x = b.x + rB.x; recB[q].y = b.y + rB.y; recB[q].z = b.z + rB.z; recB[q].w = b.w + rB.w;
    }

    // prefetch c=0 masked values
    float a0 = us2f(masked_T[(size_t)0 * N_NODES + mA]);
    float a1 = us2f(masked_T[(size_t)1 * N_NODES + mA]);
    float a2 = us2f(masked_T[(size_t)2 * N_NODES + mA]);
    float a3 = us2f(masked_T[(size_t)3 * N_NODES + mA]);
    float b0 = us2f(masked_T[(size_t)0 * N_NODES + mB]);
    float b1 = us2f(masked_T[(size_t)1 * N_NODES + mB]);
    float b2 = us2f(masked_T[(size_t)2 * N_NODES + mB]);
    float b3 = us2f(masked_T[(size_t)3 * N_NODES + mB]);

    for (int c = 0; c < 32; ++c) {
        // prefetch next c (clamped)
        int cn = (c < 31) ? (c + 1) : 31;
        size_t rb = (size_t)(cn * 4) * N_NODES;
        float na0 = us2f(masked_T[rb + mA]);
        float na1 = us2f(masked_T[rb + N_NODES + mA]);
        float na2 = us2f(masked_T[rb + 2u * N_NODES + mA]);
        float na3 = us2f(masked_T[rb + 3u * N_NODES + mA]);
        float nb0 = us2f(masked_T[rb + mB]);
        float nb1 = us2f(masked_T[rb + N_NODES + mB]);
        float nb2 = us2f(masked_T[rb + 2u * N_NODES + mB]);
        float nb3 = us2f(masked_T[rb + 3u * N_NODES + mB]);

        float4 zA = bz2s[c], zB = bz2s[c];
        #pragma unroll
        for (int g4 = 0; g4 < 8; ++g4) {
            float4 w0 = Wz1s[c * 32 + g4];
            float4 w1 = Wz1s[c * 32 + 8 + g4];
            float4 w2 = Wz1s[c * 32 + 16 + g4];
            float4 w3 = Wz1s[c * 32 + 24 + g4];
            float4 bb = bz1s[c * 8 + g4];
            float4 vA, vB;
            vA.x = bb.x + a0 * w0.x + a1 * w1.x + a2 * w2.x + a3 * w3.x;
            vA.y = bb.y + a0 * w0.y + a1 * w1.y + a2 * w2.y + a3 * w3.y;
            vA.z = bb.z + a0 * w0.z + a1 * w1.z + a2 * w2.z + a3 * w3.z;
            vA.w = bb.w + a0 * w0.w + a1 * w1.w + a2 * w2.w + a3 * w3.w;
            vB.x = bb.x + b0 * w0.x + b1 * w1.x + b2 * w2.x + b3 * w3.x;
            vB.y = bb.y + b0 * w0.y + b1 * w1.y + b2 * w2.y + b3 * w3.y;
            vB.z = bb.z + b0 * w0.z + b1 * w1.z + b2 * w2.z + b3 * w3.z;
            vB.w = bb.w + b0 * w0.w + b1 * w1.w + b2 * w2.w + b3 * w3.w;
            vA.x = elu_fast(vA.x); vA.y = elu_fast(vA.y); vA.z = elu_fast(vA.z); vA.w = elu_fast(vA.w);
            vB.x = elu_fast(vB.x); vB.y = elu_fast(vB.y); vB.z = elu_fast(vB.z); vB.w = elu_fast(vB.w);
            float4 u0 = Wz2s[c * 32 + g4 * 4 + 0];
            float4 u1 = Wz2s[c * 32 + g4 * 4 + 1];
            float4 u2 = Wz2s[c * 32 + g4 * 4 + 2];
            float4 u3 = Wz2s[c * 32 + g4 * 4 + 3];
            zA.x += vA.x * u0.x + vA.y * u1.x + vA.z * u2.x + vA.w * u3.x;
            zA.y += vA.x * u0.y + vA.y * u1.y + vA.z * u2.y + vA.w * u3.y;
            zA.z += vA.x * u0.z + vA.y * u1.z + vA.z * u2.z + vA.w * u3.z;
            zA.w += vA.x * u0.w + vA.y * u1.w + vA.z * u2.w + vA.w * u3.w;
            zB.x += vB.x * u0.x + vB.y * u1.x + vB.z * u2.x + vB.w * u3.x;
            zB.y += vB.x * u0.y + vB.y * u1.y + vB.z * u2.y + vB.w * u3.y;
            zB.z += vB.x * u0.z + vB.y * u1.z + vB.z * u2.z + vB.w * u3.z;
            zB.w += vB.x * u0.w + vB.y * u1.w + vB.z * u2.w + vB.w * u3.w;
        }
        #pragma unroll
        for (int q = 0; q < 8; ++q) {
            float4 w0 = Wrecs[(c * 4 + 0) * 8 + q];
            float4 w1 = Wrecs[(c * 4 + 1) * 8 + q];
            float4 w2 = Wrecs[(c * 4 + 2) * 8 + q];
            float4 w3 = Wrecs[(c * 4 + 3) * 8 + q];
            recA[q].x += zA.x * w0.x + zA.y * w1.x + zA.z * w2.x + zA.w * w3.x;
            recA[q].y += zA.x * w0.y + zA.y * w1.y + zA.z * w2.y + zA.w * w3.y;
            recA[q].z += zA.x * w0.z + zA.y * w1.z + zA.z * w2.z + zA.w * w3.z;
            recA[q].w += zA.x * w0.w + zA.y * w1.w + zA.z * w2.w + zA.w * w3.w;
            recB[q].x += zB.x * w0.x + zB.y * w1.x + zB.z * w2.x + zB.w * w3.x;
            recB[q].y += zB.x * w0.y + zB.y * w1.y + zB.z * w2.y + zB.w * w3.y;
            recB[q].z += zB.x * w0.z + zB.y * w1.z + zB.z * w2.z + zB.w * w3.z;
            recB[q].w += zB.x * w0.w + zB.y * w1.w + zB.z * w2.w + zB.w * w3.w;
        }
        a0 = na0; a1 = na1; a2 = na2; a3 = na3;
        b0 = nb0; b1 = nb1; b2 = nb2; b3 = nb3;
    }
    if (okA) {
        #pragma unroll
        for (int q = 0; q < 8; ++q) ((float4*)(out + (size_t)nA * 32))[q] = recA[q];
    }
    if (okB) {
        #pragma unroll
        for (int q = 0; q < 8; ++q) ((float4*)(out + (size_t)nB * 32))[q] = recB[q];
    }
}

// ---------------- label head: pred = MLP_c(A^T@label), one lane per node ---------------------
__global__ __launch_bounds__(256) void k_label(const float* __restrict__ label,
                                               const float* __restrict__ A,
                                               const float* __restrict__ Wl1,
                                               const float* __restrict__ bl1,
                                               const float* __restrict__ Wl2,
                                               const float* __restrict__ bl2,
                                               float* __restrict__ out) {
    __shared__ float As[1024], Wl1s[1024], bl1s[1024], Wl2s[1024], bl2s[32];
    int tid = threadIdx.x;
    for (int i = tid; i < 1024; i += 256) {
        As[i] = A[i];
        Wl1s[i] = Wl1[i];
        bl1s[i] = bl1[i];
        Wl2s[i] = Wl2[i];
    }
    if (tid < 32) bl2s[tid] = bl2[tid];
    __syncthreads();

    int n = blockIdx.x * 256 + tid;
    bool ok = n < N_NODES;
    int nn = ok ? n : (N_NODES - 1);

    float lab[32];
    #pragma unroll
    for (int q = 0; q < 8; ++q) {
        float4 lv = ((const float4*)(label + (size_t)nn * 32))[q];
        lab[q * 4 + 0] = lv.x; lab[q * 4 + 1] = lv.y;
        lab[q * 4 + 2] = lv.z; lab[q * 4 + 3] = lv.w;
    }
    float pred[32];
    for (int c = 0; c < 32; ++c) {
        float ml = 0.f;
        #pragma unroll
        for (int k = 0; k < 32; ++k) ml += As[k * 32 + c] * lab[k];   // A^T[c][k] = A[k][c]
        float p = bl2s[c];
        #pragma unroll
        for (int g = 0; g < 32; ++g) {
            float h = elu_fast(ml * Wl1s[c * 32 + g] + bl1s[c * 32 + g]);
            p += h * Wl2s[c * 32 + g];
        }
        pred[c] = p;
    }
    if (ok) {
        #pragma unroll
        for (int q = 0; q < 8; ++q) {
            float4 v = {pred[q * 4 + 0], pred[q * 4 + 1], pred[q * 4 + 2], pred[q * 4 + 3]};
            ((float4*)(out + (size_t)N_NODES * 32 + (size_t)n * 32))[q] = v;
        }
    }
}

extern "C" void kernel_launch(void* const* d_in, const int* in_sizes, int n_in,
                              void* d_out, int out_size, void* d_ws, size_t ws_size,
                              hipStream_t stream) {
    const float* X      = (const float*)d_in[0];
    const float* label  = (const float*)d_in[1];
    const float* evalv  = (const float*)d_in[2];
    const float* noise  = (const float*)d_in[3];
    const float* W_base = (const float*)d_in[4];
    const float* W_mean = (const float*)d_in[5];
    // d_in[6] = W_logstd : dead code in the reference
    const float* A      = (const float*)d_in[7];
    const float* Wz1    = (const float*)d_in[8];
    const float* bz1    = (const float*)d_in[9];
    const float* Wz2    = (const float*)d_in[10];
    const float* bz2    = (const float*)d_in[11];
    const float* Wl1    = (const float*)d_in[12];
    const float* bl1    = (const float*)d_in[13];
    const float* Wl2    = (const float*)d_in[14];
    const float* bl2    = (const float*)d_in[15];
    const float* Wrec   = (const float*)d_in[16];
    const float* brec   = (const float*)d_in[17];
    const int* esrc = (const int*)d_in[18];
    const int* edst = (const int*)d_in[19];
    float* out = (float*)d_out;

    char* ws = (char*)d_ws;
    // Layout (~62.3 MB total; <= proven-safe 73.3 MB):
    float*          Wcomb       = (float*)(ws);                        // @0        64 KB
    float*          MmT         = (float*)(ws + 65536);                // @65536    4 KB
    unsigned int*   blk_sums    = (unsigned int*)(ws + 69632);         // @69632    1 KB
    unsigned int*   deg         = (unsigned int*)(ws + 70656);         // padded 100352 u32
    unsigned int*   row_start   = (unsigned int*)(ws + 472064);        // N+1 u32
    unsigned int*   cursor      = (unsigned int*)(ws + 873984);        // N u32
    uint2*          edge_sorted = (uint2*)(ws + 1273984);              // 12.8 MB
    // slot A (25.6 MB): hidden (bf16) -> masked_T (bf16, transposed)
    unsigned short* hidden      = (unsigned short*)(ws + 14073984);
    unsigned short* masked_T    = (unsigned short*)(ws + 14073984);
    // slot B (25.6 MB): S1 (f32) -> S2 (bf16) -> rec_noise (f32)
    float*          S1          = (float*)(ws + 39673984);
    unsigned short* S2          = (unsigned short*)(ws + 39673984);
    float*          rec_noise   = (float*)(ws + 39673984);

    hipMemsetAsync(deg, 0, 100352 * sizeof(unsigned int), stream);
    k_inv<<<1, 64, 0, stream>>>(A, MmT);
    k_fold<<<16, 256, 0, stream>>>(MmT, W_mean, Wcomb);
    k_hist<<<N_EDGES / 256, 256, 0, stream>>>(edst, deg);
    k_scanA<<<98, 256, 0, stream>>>(deg, row_start, blk_sums);
    k_scanB<<<1, 128, 0, stream>>>(blk_sums);
    k_scanC<<<98, 256, 0, stream>>>(row_start, cursor, blk_sums);
    k_scatter<<<N_EDGES / 256, 256, 0, stream>>>(esrc, edst, evalv, cursor, edge_sorted);
    k_gather1<<<N_NODES / 8, 256, 0, stream>>>(row_start, edge_sorted, X, S1);
    k_gemm1<<<N_NODES / 32, 256, 0, stream>>>(S1, W_base, hidden);
    k_gather2<<<N_NODES / 8, 256, 0, stream>>>(row_start, edge_sorted, hidden, S2);
    k_gemm2<<<(N_NODES / 32) * 2, 256, 0, stream>>>(S2, Wcomb, masked_T);
    k_noise<<<(N_NODES + 63) / 64, 256, 0, stream>>>(noise, Wrec, rec_noise);
    k_nodez<<<(N_NODES + 127) / 128, 64, 0, stream>>>(masked_T, rec_noise,
                                                      Wz1, bz1, Wz2, bz2, Wrec, brec, out);
    k_label<<<(N_NODES + 255) / 256, 256, 0, stream>>>(label, A, Wl1, bl1, Wl2, bl2, out);
}

// Round 9
// 753.988 us; speedup vs baseline: 1.2923x; 1.2923x over previous
//
#include <hip/hip_runtime.h>
#include <hip/hip_bf16.h>

#define N_NODES 100000
#define N_EDGES 1600000

static __device__ __forceinline__ float us2f(unsigned short u) {
    union { unsigned int i; float f; } cv; cv.i = ((unsigned int)u) << 16; return cv.f;
}
static __device__ __forceinline__ unsigned short f2us(float f) {
    __hip_bfloat16 b = __float2bfloat16(f);
    union { __hip_bfloat16 b; unsigned short u; } cv; cv.b = b; return cv.u;
}
static __device__ __forceinline__ float elu_fast(float v) {
    return v > 0.f ? v : (__expf(v) - 1.0f);
}

// ---------------- inv: single-wave Gauss-Jordan; outputs MmT[j*32+c] = (A^T (I-A^T)^{-1})[c][j]
__global__ __launch_bounds__(64) void k_inv(const float* __restrict__ A,
                                            float* __restrict__ MmT) {
    __shared__ float Af[1024];
    __shared__ float aug[32 * 65];
    __shared__ float fac[32];
    __shared__ float pv_s;
    int t = threadIdx.x;
    for (int i = t; i < 1024; i += 64) Af[i] = A[i];
    __syncthreads();
    for (int i = t; i < 2048; i += 64) {
        int r = i >> 6, c = i & 63;
        float v;
        if (c < 32) v = (r == c ? 1.0f : 0.0f) - Af[c * 32 + r];
        else        v = ((c - 32) == r ? 1.0f : 0.0f);
        aug[r * 65 + c] = v;
    }
    __syncthreads();
    for (int k = 0; k < 32; ++k) {
        if (t == 0) pv_s = 1.0f / aug[k * 65 + k];
        __syncthreads();
        aug[k * 65 + t] *= pv_s;
        __syncthreads();
        if (t < 32) fac[t] = aug[t * 65 + k];
        __syncthreads();
        #pragma unroll 4
        for (int i = t; i < 2048; i += 64) {
            int r = i >> 6, c = i & 63;
            if (r != k) aug[r * 65 + c] -= fac[r] * aug[k * 65 + c];
        }
        __syncthreads();
    }
    for (int i = t; i < 1024; i += 64) {
        int j = i >> 5, c = i & 31;
        float s = 0.f;
        #pragma unroll
        for (int k = 0; k < 32; ++k) s += Af[k * 32 + c] * aug[k * 65 + 32 + j];
        MmT[i] = s;
    }
}

// ---------------- fold: Wcomb[h][c*4+d] = sum_j Mm[c][j]*Wm[h*128+j*4+d]  (16 blocks) --------
__global__ __launch_bounds__(256) void k_fold(const float* __restrict__ MmT,
                                              const float* __restrict__ Wm,
                                              float* __restrict__ Wcomb) {
    __shared__ float MmTs[1024];
    int tid = threadIdx.x;
    for (int i = tid; i < 1024; i += 256) MmTs[i] = MmT[i];
    __syncthreads();
    int o = blockIdx.x * 256 + tid;
    int h = o >> 5, c = o & 31;
    float4 s = {0.f, 0.f, 0.f, 0.f};
    #pragma unroll
    for (int j = 0; j < 32; ++j) {
        float m = MmTs[j * 32 + c];
        float4 w = ((const float4*)Wm)[h * 32 + j];
        s.x += m * w.x; s.y += m * w.y; s.z += m * w.z; s.w += m * w.w;
    }
    ((float4*)Wcomb)[o] = s;
}

// ---------------- CSR build: histogram -> multi-block scan -> scatter ------------------------
__global__ __launch_bounds__(256) void k_hist(const int* __restrict__ edst,
                                              unsigned int* __restrict__ deg) {
    int e = blockIdx.x * 256 + threadIdx.x;
    atomicAdd(&deg[edst[e]], 1u);
}

__global__ __launch_bounds__(256) void k_scanA(const unsigned int* __restrict__ deg,
                                               unsigned int* __restrict__ row_start,
                                               unsigned int* __restrict__ blk_sums) {
    __shared__ unsigned int sums[256];
    int tid = threadIdx.x;
    int gid = blockIdx.x * 256 + tid;
    uint4 d = ((const uint4*)deg)[gid];
    unsigned int p1 = d.x, p2 = d.x + d.y, p3 = p2 + d.z;
    unsigned int tsum = p3 + d.w;
    sums[tid] = tsum;
    __syncthreads();
    for (int off = 1; off < 256; off <<= 1) {
        unsigned int v = (tid >= off) ? sums[tid - off] : 0u;
        __syncthreads();
        sums[tid] += v;
        __syncthreads();
    }
    unsigned int excl = sums[tid] - tsum;
    int eb = gid * 4;
    if (eb + 0 < N_NODES) row_start[eb + 0] = excl;
    if (eb + 1 < N_NODES) row_start[eb + 1] = excl + p1;
    if (eb + 2 < N_NODES) row_start[eb + 2] = excl + p2;
    if (eb + 3 < N_NODES) row_start[eb + 3] = excl + p3;
    if (tid == 255) blk_sums[blockIdx.x] = sums[255];
}

__global__ __launch_bounds__(128) void k_scanB(unsigned int* __restrict__ blk_sums) {
    __shared__ unsigned int s[128];
    int tid = threadIdx.x;
    unsigned int v = (tid < 98) ? blk_sums[tid] : 0u;
    s[tid] = v;
    __syncthreads();
    for (int off = 1; off < 128; off <<= 1) {
        unsigned int x = (tid >= off) ? s[tid - off] : 0u;
        __syncthreads();
        s[tid] += x;
        __syncthreads();
    }
    if (tid < 98) blk_sums[tid] = s[tid] - v;
}

__global__ __launch_bounds__(256) void k_scanC(unsigned int* __restrict__ row_start,
                                               unsigned int* __restrict__ cursor,
                                               const unsigned int* __restrict__ blk_sums) {
    int tid = threadIdx.x;
    unsigned int off = blk_sums[blockIdx.x];
    int eb = (blockIdx.x * 256 + tid) * 4;
    #pragma unroll
    for (int k = 0; k < 4; ++k) {
        int idx = eb + k;
        if (idx < N_NODES) {
            unsigned int u = row_start[idx] + off;
            row_start[idx] = u;
            cursor[idx] = u;
        }
    }
    if (blockIdx.x == 0 && tid == 0) row_start[N_NODES] = N_EDGES;
}

__global__ __launch_bounds__(256) void k_scatter(const int* __restrict__ esrc,
                                                 const int* __restrict__ edst,
                                                 const float* __restrict__ evalv,
                                                 unsigned int* __restrict__ cursor,
                                                 uint2* __restrict__ edge_sorted) {
    int e = blockIdx.x * 256 + threadIdx.x;
    unsigned int p = atomicAdd(&cursor[edst[e]], 1u);
    uint2 ev;
    ev.x = (unsigned int)esrc[e];
    ev.y = __float_as_uint(evalv[e]);
    edge_sorted[p] = ev;
}

// ---------------- gather1: S1[n][c] = sum_e val*X[src][c]  (no LDS, unroll x4) ---------------
__global__ __launch_bounds__(256) void k_gather1(const unsigned int* __restrict__ row_start,
                                                 const uint2* __restrict__ edge_sorted,
                                                 const float* __restrict__ X,
                                                 float* __restrict__ S1) {
    int lane = threadIdx.x & 31;
    int n = blockIdx.x * 8 + (threadIdx.x >> 5);
    unsigned int i = row_start[n], e = row_start[n + 1];
    float a0 = 0.f, a1 = 0.f, a2 = 0.f, a3 = 0.f;
    for (; i + 4 <= e; i += 4) {
        uint2 ea = edge_sorted[i + 0], eb = edge_sorted[i + 1];
        uint2 ec = edge_sorted[i + 2], ed = edge_sorted[i + 3];
        float xa = X[(size_t)ea.x * 32 + lane];
        float xb = X[(size_t)eb.x * 32 + lane];
        float xc = X[(size_t)ec.x * 32 + lane];
        float xd = X[(size_t)ed.x * 32 + lane];
        a0 += __uint_as_float(ea.y) * xa;
        a1 += __uint_as_float(eb.y) * xb;
        a2 += __uint_as_float(ec.y) * xc;
        a3 += __uint_as_float(ed.y) * xd;
    }
    for (; i < e; ++i) {
        uint2 ea = edge_sorted[i];
        a0 += __uint_as_float(ea.y) * X[(size_t)ea.x * 32 + lane];
    }
    S1[(size_t)n * 32 + lane] = (a0 + a1) + (a2 + a3);
}

// ---------------- gemm1: hidden = bf16(relu(S1 @ W_base)), [32 rows x 128 cols]/block --------
__global__ __launch_bounds__(256) void k_gemm1(const float* __restrict__ S1,
                                               const float* __restrict__ Wb,
                                               unsigned short* __restrict__ hidden) {
    __shared__ float Wb_s[4096];
    __shared__ float S1s[32 * 36];
    int tid = threadIdx.x;
    int n0 = blockIdx.x * 32;
    for (int i = tid; i < 1024; i += 256)
        ((float4*)Wb_s)[i] = ((const float4*)Wb)[i];
    {
        int r = tid >> 3, cq = tid & 7;
        *(float4*)&S1s[r * 36 + cq * 4] = *(const float4*)&S1[(size_t)(n0 + r) * 32 + cq * 4];
    }
    __syncthreads();
    int q = (tid & 31) * 4;
    int r0 = tid >> 5;
    float4 acc[4];
    #pragma unroll
    for (int i = 0; i < 4; ++i) acc[i] = make_float4(0.f, 0.f, 0.f, 0.f);
    for (int k4 = 0; k4 < 32; k4 += 4) {
        float4 s[4];
        #pragma unroll
        for (int i = 0; i < 4; ++i) s[i] = *(const float4*)&S1s[(r0 + i * 8) * 36 + k4];
        #pragma unroll
        for (int kk = 0; kk < 4; ++kk) {
            float4 w = *(const float4*)&Wb_s[(k4 + kk) * 128 + q];
            #pragma unroll
            for (int i = 0; i < 4; ++i) {
                float v = (&s[i].x)[kk];
                acc[i].x += v * w.x; acc[i].y += v * w.y;
                acc[i].z += v * w.z; acc[i].w += v * w.w;
            }
        }
    }
    #pragma unroll
    for (int i = 0; i < 4; ++i) {
        ushort4 o;
        o.x = f2us(fmaxf(acc[i].x, 0.f)); o.y = f2us(fmaxf(acc[i].y, 0.f));
        o.z = f2us(fmaxf(acc[i].z, 0.f)); o.w = f2us(fmaxf(acc[i].w, 0.f));
        *(ushort4*)&hidden[(size_t)(n0 + r0 + i * 8) * 128 + q] = o;
    }
}

// ---------------- gather2: S2[n][0:128] (bf16) = sum_e val*hidden[src]  (no LDS, unroll x4) ---
__global__ __launch_bounds__(256) void k_gather2(const unsigned int* __restrict__ row_start,
                                                 const uint2* __restrict__ edge_sorted,
                                                 const unsigned short* __restrict__ hidden,
                                                 unsigned short* __restrict__ S2) {
    int lane = threadIdx.x & 31;
    int n = blockIdx.x * 8 + (threadIdx.x >> 5);
    unsigned int i = row_start[n], e = row_start[n + 1];
    float4 A0 = {0, 0, 0, 0}, A1 = {0, 0, 0, 0}, A2 = {0, 0, 0, 0}, A3 = {0, 0, 0, 0};
    for (; i + 4 <= e; i += 4) {
        uint2 ea = edge_sorted[i + 0], eb = edge_sorted[i + 1];
        uint2 ec = edge_sorted[i + 2], ed = edge_sorted[i + 3];
        ushort4 ha = *(const ushort4*)&hidden[(size_t)ea.x * 128 + lane * 4];
        ushort4 hb = *(const ushort4*)&hidden[(size_t)eb.x * 128 + lane * 4];
        ushort4 hc = *(const ushort4*)&hidden[(size_t)ec.x * 128 + lane * 4];
        ushort4 hd = *(const ushort4*)&hidden[(size_t)ed.x * 128 + lane * 4];
        float va = __uint_as_float(ea.y), vb = __uint_as_float(eb.y);
        float vc = __uint_as_float(ec.y), vd = __uint_as_float(ed.y);
        A0.x += va * us2f(ha.x); A0.y += va * us2f(ha.y); A0.z += va * us2f(ha.z); A0.w += va * us2f(ha.w);
        A1.x += vb * us2f(hb.x); A1.y += vb * us2f(hb.y); A1.z += vb * us2f(hb.z); A1.w += vb * us2f(hb.w);
        A2.x += vc * us2f(hc.x); A2.y += vc * us2f(hc.y); A2.z += vc * us2f(hc.z); A2.w += vc * us2f(hc.w);
        A3.x += vd * us2f(hd.x); A3.y += vd * us2f(hd.y); A3.z += vd * us2f(hd.z); A3.w += vd * us2f(hd.w);
    }
    for (; i < e; ++i) {
        uint2 ea = edge_sorted[i];
        float v = __uint_as_float(ea.y);
        ushort4 h = *(const ushort4*)&hidden[(size_t)ea.x * 128 + lane * 4];
        A0.x += v * us2f(h.x); A0.y += v * us2f(h.y); A0.z += v * us2f(h.z); A0.w += v * us2f(h.w);
    }
    float4 acc;
    acc.x = (A0.x + A1.x) + (A2.x + A3.x);
    acc.y = (A0.y + A1.y) + (A2.y + A3.y);
    acc.z = (A0.z + A1.z) + (A2.z + A3.z);
    acc.w = (A0.w + A1.w) + (A2.w + A3.w);
    ushort4 o;
    o.x = f2us(acc.x); o.y = f2us(acc.y); o.z = f2us(acc.z); o.w = f2us(acc.w);
    *(ushort4*)&S2[(size_t)n * 128 + lane * 4] = o;
}

// ---------------- gemm2: masked_T = (S2 @ Wcomb)^T, [32 rows x 64 cols]/block ----------------
__global__ __launch_bounds__(256) void k_gemm2(const unsigned short* __restrict__ S2,
                                               const float* __restrict__ Wc,
                                               unsigned short* __restrict__ masked_T) {
    __shared__ float Wc_s[128 * 64];
    __shared__ float S2s[32 * 132];
    __shared__ unsigned short Tt[64 * 40];
    int tid = threadIdx.x;
    int rb = blockIdx.x >> 1;
    int j0 = (blockIdx.x & 1) * 64;
    int n0 = rb * 32;
    for (int idx = tid; idx < 2048; idx += 256) {
        int k = idx >> 4, jq = idx & 15;
        *(float4*)&Wc_s[k * 64 + jq * 4] = *(const float4*)&Wc[k * 128 + j0 + jq * 4];
    }
    for (int idx = tid; idx < 1024; idx += 256) {
        int r = idx >> 5, kq = idx & 31;
        ushort4 h = *(const ushort4*)&S2[(size_t)(n0 + r) * 128 + kq * 4];
        float4 f = {us2f(h.x), us2f(h.y), us2f(h.z), us2f(h.w)};
        *(float4*)&S2s[r * 132 + kq * 4] = f;
    }
    __syncthreads();
    int q = (tid & 15) * 4;
    int r0 = tid >> 4;
    float4 a0 = {0, 0, 0, 0}, a1 = {0, 0, 0, 0};
    for (int k4 = 0; k4 < 128; k4 += 4) {
        float4 s0 = *(const float4*)&S2s[r0 * 132 + k4];
        float4 s1 = *(const float4*)&S2s[(r0 + 16) * 132 + k4];
        #pragma unroll
        for (int kk = 0; kk < 4; ++kk) {
            float v0 = (&s0.x)[kk];
            float v1 = (&s1.x)[kk];
            float4 w = *(const float4*)&Wc_s[(k4 + kk) * 64 + q];
            a0.x += v0 * w.x; a0.y += v0 * w.y; a0.z += v0 * w.z; a0.w += v0 * w.w;
            a1.x += v1 * w.x; a1.y += v1 * w.y; a1.z += v1 * w.z; a1.w += v1 * w.w;
        }
    }
    #pragma unroll
    for (int c = 0; c < 4; ++c) {
        Tt[(q + c) * 40 + r0]      = f2us((&a0.x)[c]);
        Tt[(q + c) * 40 + r0 + 16] = f2us((&a1.x)[c]);
    }
    __syncthreads();
    int j = tid >> 2, seg = tid & 3;
    uint4 pk = *(const uint4*)&Tt[j * 40 + seg * 8];
    *(uint4*)&masked_T[(size_t)(j0 + j) * N_NODES + n0 + seg * 8] = pk;
}

// ---------------- nodez: per-concept MLP only -> mlpz[n][128] bf16 ---------------------------
// 128 threads, 2 nodes/lane, ~37 KB LDS -> 4 blocks/CU. All weight reads b128 broadcasts.
__global__ __launch_bounds__(128) void k_nodez(const unsigned short* __restrict__ masked_T,
                                               const float* __restrict__ Wz1,
                                               const float* __restrict__ bz1,
                                               const float* __restrict__ Wz2,
                                               const float* __restrict__ bz2,
                                               unsigned short* __restrict__ mlpz) {
    __shared__ float4 Wz1s[1024];   // [c][d][g/4]: c*32 + d*8 + g4   (16 KB)
    __shared__ float4 Wz2s[1024];   // [c][g] over d                  (16 KB)
    __shared__ float4 bz1s[256];    // [c][g/4]                       (4 KB)
    __shared__ float4 bz2s[32];     // [c] over d                     (0.5 KB)
    int tid = threadIdx.x;
    for (int i = tid; i < 1024; i += 128) {
        Wz1s[i] = ((const float4*)Wz1)[i];
        Wz2s[i] = ((const float4*)Wz2)[i];
    }
    for (int i = tid; i < 256; i += 128) bz1s[i] = ((const float4*)bz1)[i];
    if (tid < 32) bz2s[tid] = ((const float4*)bz2)[tid];
    __syncthreads();

    int nA = blockIdx.x * 256 + tid;
    int nB = nA + 128;
    bool okA = nA < N_NODES, okB = nB < N_NODES;
    int mA = okA ? nA : (N_NODES - 1);
    int mB = okB ? nB : (N_NODES - 1);

    // prefetch c=0 masked values
    float a0 = us2f(masked_T[(size_t)0 * N_NODES + mA]);
    float a1 = us2f(masked_T[(size_t)1 * N_NODES + mA]);
    float a2 = us2f(masked_T[(size_t)2 * N_NODES + mA]);
    float a3 = us2f(masked_T[(size_t)3 * N_NODES + mA]);
    float b0 = us2f(masked_T[(size_t)0 * N_NODES + mB]);
    float b1 = us2f(masked_T[(size_t)1 * N_NODES + mB]);
    float b2 = us2f(masked_T[(size_t)2 * N_NODES + mB]);
    float b3 = us2f(masked_T[(size_t)3 * N_NODES + mB]);

    for (int c = 0; c < 32; ++c) {
        int cn = (c < 31) ? (c + 1) : 31;
        size_t rbase = (size_t)(cn * 4) * N_NODES;
        float na0 = us2f(masked_T[rbase + mA]);
        float na1 = us2f(masked_T[rbase + N_NODES + mA]);
        float na2 = us2f(masked_T[rbase + 2u * N_NODES + mA]);
        float na3 = us2f(masked_T[rbase + 3u * N_NODES + mA]);
        float nb0 = us2f(masked_T[rbase + mB]);
        float nb1 = us2f(masked_T[rbase + N_NODES + mB]);
        float nb2 = us2f(masked_T[rbase + 2u * N_NODES + mB]);
        float nb3 = us2f(masked_T[rbase + 3u * N_NODES + mB]);

        float4 zA = bz2s[c], zB = bz2s[c];
        #pragma unroll
        for (int g4 = 0; g4 < 8; ++g4) {
            float4 w0 = Wz1s[c * 32 + g4];
            float4 w1 = Wz1s[c * 32 + 8 + g4];
            float4 w2 = Wz1s[c * 32 + 16 + g4];
            float4 w3 = Wz1s[c * 32 + 24 + g4];
            float4 bb = bz1s[c * 8 + g4];
            float4 vA, vB;
            vA.x = bb.x + a0 * w0.x + a1 * w1.x + a2 * w2.x + a3 * w3.x;
            vA.y = bb.y + a0 * w0.y + a1 * w1.y + a2 * w2.y + a3 * w3.y;
            vA.z = bb.z + a0 * w0.z + a1 * w1.z + a2 * w2.z + a3 * w3.z;
            vA.w = bb.w + a0 * w0.w + a1 * w1.w + a2 * w2.w + a3 * w3.w;
            vB.x = bb.x + b0 * w0.x + b1 * w1.x + b2 * w2.x + b3 * w3.x;
            vB.y = bb.y + b0 * w0.y + b1 * w1.y + b2 * w2.y + b3 * w3.y;
            vB.z = bb.z + b0 * w0.z + b1 * w1.z + b2 * w2.z + b3 * w3.z;
            vB.w = bb.w + b0 * w0.w + b1 * w1.w + b2 * w2.w + b3 * w3.w;
            vA.x = elu_fast(vA.x); vA.y = elu_fast(vA.y); vA.z = elu_fast(vA.z); vA.w = elu_fast(vA.w);
            vB.x = elu_fast(vB.x); vB.y = elu_fast(vB.y); vB.z = elu_fast(vB.z); vB.w = elu_fast(vB.w);
            float4 u0 = Wz2s[c * 32 + g4 * 4 + 0];
            float4 u1 = Wz2s[c * 32 + g4 * 4 + 1];
            float4 u2 = Wz2s[c * 32 + g4 * 4 + 2];
            float4 u3 = Wz2s[c * 32 + g4 * 4 + 3];
            zA.x += vA.x * u0.x + vA.y * u1.x + vA.z * u2.x + vA.w * u3.x;
            zA.y += vA.x * u0.y + vA.y * u1.y + vA.z * u2.y + vA.w * u3.y;
            zA.z += vA.x * u0.z + vA.y * u1.z + vA.z * u2.z + vA.w * u3.z;
            zA.w += vA.x * u0.w + vA.y * u1.w + vA.z * u2.w + vA.w * u3.w;
            zB.x += vB.x * u0.x + vB.y * u1.x + vB.z * u2.x + vB.w * u3.x;
            zB.y += vB.x * u0.y + vB.y * u1.y + vB.z * u2.y + vB.w * u3.y;
            zB.z += vB.x * u0.z + vB.y * u1.z + vB.z * u2.z + vB.w * u3.z;
            zB.w += vB.x * u0.w + vB.y * u1.w + vB.z * u2.w + vB.w * u3.w;
        }
        if (okA) {
            ushort4 o; o.x = f2us(zA.x); o.y = f2us(zA.y); o.z = f2us(zA.z); o.w = f2us(zA.w);
            *(ushort4*)&mlpz[(size_t)nA * 128 + c * 4] = o;
        }
        if (okB) {
            ushort4 o; o.x = f2us(zB.x); o.y = f2us(zB.y); o.z = f2us(zB.z); o.w = f2us(zB.w);
            *(ushort4*)&mlpz[(size_t)nB * 128 + c * 4] = o;
        }
        a0 = na0; a1 = na1; a2 = na2; a3 = na3;
        b0 = nb0; b1 = nb1; b2 = nb2; b3 = nb3;
    }
}

// ---------------- rec head: out = (mlpz + sqrt(lambda)*noise) @ Wrec + brec ------------------
__global__ __launch_bounds__(256) void k_rec(const unsigned short* __restrict__ mlpz,
                                             const float* __restrict__ noise,
                                             const float* __restrict__ Wrec,
                                             const float* __restrict__ brec,
                                             float* __restrict__ out) {
    __shared__ float Wr[4096];        // [k][o] 128x32 (16 KB)
    __shared__ float Ns[64 * 132];    // fused z+noise rows (33.8 KB)
    __shared__ float brs[32];
    int tid = threadIdx.x;
    int n0 = blockIdx.x * 64;
    const float SQ = 0.03162277660168379f;
    for (int i = tid; i < 1024; i += 256)
        ((float4*)Wr)[i] = ((const float4*)Wrec)[i];
    if (tid < 32) brs[tid] = brec[tid];
    for (int i = tid; i < 1024; i += 256) {
        int row = i >> 4, u8 = i & 15;       // 8 cols per chunk
        int n = n0 + row;
        float vals[8];
        if (n < N_NODES) {
            uint4 zz = ((const uint4*)(mlpz + (size_t)n * 128))[u8];
            float4 f0 = ((const float4*)(noise + (size_t)n * 128))[u8 * 2];
            float4 f1 = ((const float4*)(noise + (size_t)n * 128))[u8 * 2 + 1];
            vals[0] = __uint_as_float(zz.x << 16)          + SQ * f0.x;
            vals[1] = __uint_as_float(zz.x & 0xffff0000u)  + SQ * f0.y;
            vals[2] = __uint_as_float(zz.y << 16)          + SQ * f0.z;
            vals[3] = __uint_as_float(zz.y & 0xffff0000u)  + SQ * f0.w;
            vals[4] = __uint_as_float(zz.z << 16)          + SQ * f1.x;
            vals[5] = __uint_as_float(zz.z & 0xffff0000u)  + SQ * f1.y;
            vals[6] = __uint_as_float(zz.w << 16)          + SQ * f1.z;
            vals[7] = __uint_as_float(zz.w & 0xffff0000u)  + SQ * f1.w;
        } else {
            #pragma unroll
            for (int j = 0; j < 8; ++j) vals[j] = 0.f;
        }
        *(float4*)&Ns[row * 132 + u8 * 8]     = make_float4(vals[0], vals[1], vals[2], vals[3]);
        *(float4*)&Ns[row * 132 + u8 * 8 + 4] = make_float4(vals[4], vals[5], vals[6], vals[7]);
    }
    __syncthreads();
    int r = tid >> 2, q = (tid & 3) * 8;
    float4 acc0 = {0, 0, 0, 0}, acc1 = {0, 0, 0, 0};
    for (int k = 0; k < 128; ++k) {
        float nv = Ns[r * 132 + k];
        float4 w0 = *(const float4*)&Wr[k * 32 + q];
        float4 w1 = *(const float4*)&Wr[k * 32 + q + 4];
        acc0.x += nv * w0.x; acc0.y += nv * w0.y; acc0.z += nv * w0.z; acc0.w += nv * w0.w;
        acc1.x += nv * w1.x; acc1.y += nv * w1.y; acc1.z += nv * w1.z; acc1.w += nv * w1.w;
    }
    int n = n0 + r;
    if (n < N_NODES) {
        acc0.x += brs[q];     acc0.y += brs[q + 1]; acc0.z += brs[q + 2]; acc0.w += brs[q + 3];
        acc1.x += brs[q + 4]; acc1.y += brs[q + 5]; acc1.z += brs[q + 6]; acc1.w += brs[q + 7];
        ((float4*)(out + (size_t)n * 32 + q))[0] = acc0;
        ((float4*)(out + (size_t)n * 32 + q + 4))[0] = acc1;
    }
}

// ---------------- label head: pred = MLP_c(A^T@label), one lane per node ---------------------
__global__ __launch_bounds__(256) void k_label(const float* __restrict__ label,
                                               const float* __restrict__ A,
                                               const float* __restrict__ Wl1,
                                               const float* __restrict__ bl1,
                                               const float* __restrict__ Wl2,
                                               const float* __restrict__ bl2,
                                               float* __restrict__ out) {
    __shared__ float As[1024], Wl1s[1024], bl1s[1024], Wl2s[1024], bl2s[32];
    int tid = threadIdx.x;
    for (int i = tid; i < 1024; i += 256) {
        As[i] = A[i];
        Wl1s[i] = Wl1[i];
        bl1s[i] = bl1[i];
        Wl2s[i] = Wl2[i];
    }
    if (tid < 32) bl2s[tid] = bl2[tid];
    __syncthreads();

    int n = blockIdx.x * 256 + tid;
    bool ok = n < N_NODES;
    int nn = ok ? n : (N_NODES - 1);

    float lab[32];
    #pragma unroll
    for (int q = 0; q < 8; ++q) {
        float4 lv = ((const float4*)(label + (size_t)nn * 32))[q];
        lab[q * 4 + 0] = lv.x; lab[q * 4 + 1] = lv.y;
        lab[q * 4 + 2] = lv.z; lab[q * 4 + 3] = lv.w;
    }
    float pred[32];
    for (int c = 0; c < 32; ++c) {
        float ml = 0.f;
        #pragma unroll
        for (int k = 0; k < 32; ++k) ml += As[k * 32 + c] * lab[k];
        float p = bl2s[c];
        #pragma unroll
        for (int g = 0; g < 32; ++g) {
            float h = elu_fast(ml * Wl1s[c * 32 + g] + bl1s[c * 32 + g]);
            p += h * Wl2s[c * 32 + g];
        }
        pred[c] = p;
    }
    if (ok) {
        #pragma unroll
        for (int q = 0; q < 8; ++q) {
            float4 v = {pred[q * 4 + 0], pred[q * 4 + 1], pred[q * 4 + 2], pred[q * 4 + 3]};
            ((float4*)(out + (size_t)N_NODES * 32 + (size_t)n * 32))[q] = v;
        }
    }
}

extern "C" void kernel_launch(void* const* d_in, const int* in_sizes, int n_in,
                              void* d_out, int out_size, void* d_ws, size_t ws_size,
                              hipStream_t stream) {
    const float* X      = (const float*)d_in[0];
    const float* label  = (const float*)d_in[1];
    const float* evalv  = (const float*)d_in[2];
    const float* noise  = (const float*)d_in[3];
    const float* W_base = (const float*)d_in[4];
    const float* W_mean = (const float*)d_in[5];
    // d_in[6] = W_logstd : dead code in the reference
    const float* A      = (const float*)d_in[7];
    const float* Wz1    = (const float*)d_in[8];
    const float* bz1    = (const float*)d_in[9];
    const float* Wz2    = (const float*)d_in[10];
    const float* bz2    = (const float*)d_in[11];
    const float* Wl1    = (const float*)d_in[12];
    const float* bl1    = (const float*)d_in[13];
    const float* Wl2    = (const float*)d_in[14];
    const float* bl2    = (const float*)d_in[15];
    const float* Wrec   = (const float*)d_in[16];
    const float* brec   = (const float*)d_in[17];
    const int* esrc = (const int*)d_in[18];
    const int* edst = (const int*)d_in[19];
    float* out = (float*)d_out;

    char* ws = (char*)d_ws;
    // Layout (~62.3 MB total; <= proven-safe 73.3 MB):
    float*          Wcomb       = (float*)(ws);                        // 64 KB
    float*          MmT         = (float*)(ws + 65536);                // 4 KB
    unsigned int*   blk_sums    = (unsigned int*)(ws + 69632);         // 1 KB
    unsigned int*   deg         = (unsigned int*)(ws + 70656);         // padded 100352 u32
    unsigned int*   row_start   = (unsigned int*)(ws + 472064);        // N+1 u32
    unsigned int*   cursor      = (unsigned int*)(ws + 873984);        // N u32
    uint2*          edge_sorted = (uint2*)(ws + 1273984);              // 12.8 MB
    // slot A (25.6 MB): hidden (bf16) -> masked_T (bf16, transposed)
    unsigned short* hidden      = (unsigned short*)(ws + 14073984);
    unsigned short* masked_T    = (unsigned short*)(ws + 14073984);
    // slot B (25.6 MB): S1 (f32) -> S2 (bf16) -> mlpz (bf16)
    float*          S1          = (float*)(ws + 39673984);
    unsigned short* S2          = (unsigned short*)(ws + 39673984);
    unsigned short* mlpz        = (unsigned short*)(ws + 39673984);

    hipMemsetAsync(deg, 0, 100352 * sizeof(unsigned int), stream);
    k_inv<<<1, 64, 0, stream>>>(A, MmT);
    k_fold<<<16, 256, 0, stream>>>(MmT, W_mean, Wcomb);
    k_hist<<<N_EDGES / 256, 256, 0, stream>>>(edst, deg);
    k_scanA<<<98, 256, 0, stream>>>(deg, row_start, blk_sums);
    k_scanB<<<1, 128, 0, stream>>>(blk_sums);
    k_scanC<<<98, 256, 0, stream>>>(row_start, cursor, blk_sums);
    k_scatter<<<N_EDGES / 256, 256, 0, stream>>>(esrc, edst, evalv, cursor, edge_sorted);
    k_gather1<<<N_NODES / 8, 256, 0, stream>>>(row_start, edge_sorted, X, S1);
    k_gemm1<<<N_NODES / 32, 256, 0, stream>>>(S1, W_base, hidden);
    k_gather2<<<N_NODES / 8, 256, 0, stream>>>(row_start, edge_sorted, hidden, S2);
    k_gemm2<<<(N_NODES / 32) * 2, 256, 0, stream>>>(S2, Wcomb, masked_T);
    k_nodez<<<(N_NODES + 255) / 256, 128, 0, stream>>>(masked_T,
                                                       Wz1, bz1, Wz2, bz2, mlpz);
    k_rec<<<(N_NODES + 63) / 64, 256, 0, stream>>>(mlpz, noise, Wrec, brec, out);
    k_label<<<(N_NODES + 255) / 256, 256, 0, stream>>>(label, A, Wl1, bl1, Wl2, bl2, out);
}